// Round 6
// baseline (658.186 us; speedup 1.0000x reference)
//
#include <hip/hip_runtime.h>
#include <cstdint>
#include <cstddef>

// ExllamaLinear: out[M,N] = f16( f16( x[M,K] @ ((q - z) * s)[K,N] ) + bias )
// M = 4096, K = 4096, N = 11008, group 128 along K. fp16 tensors stored f32.
//
// R11: faithful m201-template port at BK=32 with a ring-4 LDS buffer.
//   - 128 K-tiles of 32. LDS = 4 bufs x (A 16KB + B 16KB) = 128 KB.
//   - 2 phases per tile, each: {ds_read batch (8 or 4 b128); stage (2x
//     global_load_lds for tile T+2); SBAR; s_barrier; lgkmcnt(0)+SBAR;
//     setprio(1); 16 independent MFMA; setprio(0); [VMW(4) at ph2]; barrier}.
//   - ring distance 2: staging tile T+2 targets region (T+2)&3, disjoint
//     from T and T+1 being read -> no WAR with in-flight LDS-DMA.
//   - one counted s_waitcnt vmcnt(4) per tile (completes T+1's 4 loads,
//     issued one full tile earlier; leaves T+2's 4 in flight). Drain(0)
//     only at tile 126. Raw s_barrier everywhere (no "memory" clobber).
//   - reads: phase1 A(i0-3) 4 + B(j0-3) 4; phase2 A(i4-7) 4. 16 MFMAs per
//     phase are fully independent (single k-step) -> deep matrix pipelining.
// Prepasses: R6's verified BK=32 tiled+swizzled layout (granule g: r=g>>2,
// slot s=g&3 holds k-granule s^((r>>1)&3)); staging reads stay sequential
// 16B; ds_read_b128 frag reads conflict-free (measured 0).

typedef unsigned short u16;
typedef u16    u16x8  __attribute__((ext_vector_type(8)));
typedef __bf16 bfv8   __attribute__((ext_vector_type(8)));
typedef float  f32x4  __attribute__((ext_vector_type(4)));

#define K_DIM 4096
#define N_DIM 11008
#define GS    128
#define KT32N (K_DIM / 32)   // 128 k-tiles of 32
#define LSTR  72             // fused-fallback padded LDS stride

__device__ __forceinline__ u16 f2bf(float f) {  // RTNE f32 -> bf16 bits
  union { float f; uint32_t u; } v;
  v.f = f;
  uint32_t u = v.u + 0x7FFFu + ((v.u >> 16) & 1u);
  return (u16)(u >> 16);
}
__device__ __forceinline__ float f16r(float v) {  // fp16 round-trip (RTNE)
  return (float)(_Float16)v;
}
__device__ __forceinline__ void async_load16(const u16* g, u16* l) {
  __builtin_amdgcn_global_load_lds(
      (const __attribute__((address_space(1))) uint32_t*)g,
      (__attribute__((address_space(3))) uint32_t*)l, 16, 0, 0);
}

// ---------------------------------------------------------------------------
// Pre-pass A: x f32 -> bf16 bits, BK=32 tiles (R6-verified). Tile (mt,kt) =
// 128 rows x 32 k = 512 granules; granule g: r=g>>2, s=g&3,
// kq = s ^ ((r>>1)&3). Writes lane-sequential 16B.
// ---------------------------------------------------------------------------
__global__ __launch_bounds__(256) void convert_x32(
    const float* __restrict__ x, u16* __restrict__ xb) {
  const int kt = blockIdx.x, mt = blockIdx.y;
  const int m0 = mt * 128, k0 = kt * 32;
  u16* dst = xb + ((size_t)mt * KT32N + kt) * 4096;
#pragma unroll
  for (int i = 0; i < 2; ++i) {
    const int g = i * 256 + threadIdx.x;
    const int r = g >> 2, s = g & 3;
    const int kq = s ^ ((r >> 1) & 3);
    const float* sp = x + (size_t)(m0 + r) * K_DIM + (k0 + kq * 8);
    const f32x4 p = *(const f32x4*)sp;
    const f32x4 q = *(const f32x4*)(sp + 4);
    u16x8 o;
#pragma unroll
    for (int t = 0; t < 4; ++t) { o[t] = f2bf(p[t]); o[t + 4] = f2bf(q[t]); }
    *(u16x8*)(dst + (size_t)g * 8) = o;
  }
}

// ---------------------------------------------------------------------------
// Pre-pass B: dequant int4 -> Wt bf16 bits, BK=32 tiles (R6-verified).
// One granule = one qweight int32 (8 nibbles along K).
// ---------------------------------------------------------------------------
__global__ __launch_bounds__(256) void dequant32(
    const uint32_t* __restrict__ qweight, const uint32_t* __restrict__ qzeros,
    const float* __restrict__ scales, u16* __restrict__ wt) {
  const int kt = blockIdx.x, nt = blockIdx.y;
  const int n0 = nt * 128;
  const int gq = kt >> 2;                       // quant group = kt*32/128
  u16* dst = wt + ((size_t)nt * KT32N + kt) * 4096;
#pragma unroll
  for (int i = 0; i < 2; ++i) {
    const int g = i * 256 + threadIdx.x;
    const int r = g >> 2, s = g & 3;
    const int kq = s ^ ((r >> 1) & 3);
    const int n = n0 + r;
    const uint32_t zq = qzeros[(size_t)gq * (N_DIM / 8) + (n >> 3)];
    const int   z   = (int)((zq >> ((n & 7) * 4)) & 15u);
    const float sc  = scales[(size_t)gq * N_DIM + n];
    const float nzs = -sc * (float)z;           // w = fma(q,s,-z*s): exact in f32
    const uint32_t q = qweight[(size_t)(kt * 4 + kq) * N_DIM + n];
    u16x8 o;
#pragma unroll
    for (int t = 0; t < 8; ++t) {
      const int qv = (int)((q >> (t * 4)) & 15u);
      o[t] = f2bf(fmaf((float)qv, sc, nzs));
    }
    *(u16x8*)(dst + (size_t)g * 8) = o;
  }
}

// ---------------------------------------------------------------------------
// GEMM: 256x256 tile, BK=32, 8 waves (2M x 4N), per-wave 128x64 (8x4 frags).
// ---------------------------------------------------------------------------
#define LDF(p)  __builtin_bit_cast(bfv8, *(const u16x8*)(p))
#define BAR()   __builtin_amdgcn_s_barrier()
#define VMW_(n) asm volatile("s_waitcnt vmcnt(" #n ")")
#define VMW(n)  VMW_(n)
#define LKW0()  asm volatile("s_waitcnt lgkmcnt(0)")
#define SBAR()  __builtin_amdgcn_sched_barrier(0)

// stage half-tile h (128 rows x 32 k = 8KB) of K-tile ktt into buf dbuf
// (one global_load_lds per wave: lanes cover 64 sequential 16B granules)
#define STAGE_A32K(ktt, h, dbuf) do {                                         \
    const u16* s_ = at0 + ((size_t)(h) * KT32N + (ktt)) * 4096;               \
    async_load16(s_ + (size_t)tid * 8,                                        \
                 &As[(dbuf) * 8192 + (h) * 4096 + wave * 512]);               \
  } while (0)
#define STAGE_B32K(ktt, h, dbuf) do {                                         \
    const u16* s_ = bt0 + ((size_t)(h) * KT32N + (ktt)) * 4096;               \
    async_load16(s_ + (size_t)tid * 8,                                        \
                 &Bs[(dbuf) * 8192 + (h) * 4096 + wave * 512]);               \
  } while (0)

// read 4 A fragments i = ib..ib+3 from buffer bufl
#define RD_A4(v, ib, bufl) do {                                               \
    _Pragma("unroll")                                                         \
    for (int i_ = 0; i_ < 4; ++i_)                                            \
      v[i_] = LDF(&As[(bufl) * 8192 + aoff + ((ib) + i_) * 512 + kq]);        \
  } while (0)
// read 4 B fragments j = 0..3 from buffer bufl
#define RD_B4(v, bufl) do {                                                   \
    _Pragma("unroll")                                                         \
    for (int j_ = 0; j_ < 4; ++j_)                                            \
      v[j_] = LDF(&Bs[(bufl) * 8192 + boff + j_ * 512 + kq]);                 \
  } while (0)

// 16 independent MFMA: i = ib..ib+3 x j = 0..3, single k-step
#define MM16(ib, av, bv) do {                                                 \
    __builtin_amdgcn_s_setprio(1);                                            \
    _Pragma("unroll")                                                         \
    for (int ii_ = 0; ii_ < 4; ++ii_)                                         \
      _Pragma("unroll")                                                       \
      for (int j_ = 0; j_ < 4; ++j_)                                          \
        acc[(ib) + ii_][j_] = __builtin_amdgcn_mfma_f32_16x16x32_bf16(        \
            av[ii_], bv[j_], acc[(ib) + ii_][j_], 0, 0, 0);                   \
    __builtin_amdgcn_s_setprio(0);                                            \
  } while (0)

// one K-tile (2 phases). BUFL literal 0-3; stage dst buf = (BUFL+2)&3.
// DO_ST: stage tile T+2. VMWSTMT: the phase-2 wait (VMW(4) steady).
#define KTILE32(T, BUFL, DO_ST, VMWSTMT) do {                                 \
    /* phase 1 */                                                             \
    RD_A4(a0, 0, BUFL);                                                       \
    RD_B4(bb, BUFL);                                                          \
    if (DO_ST) {                                                              \
      STAGE_A32K((T) + 2, 0, ((BUFL) + 2) & 3);                               \
      STAGE_A32K((T) + 2, 1, ((BUFL) + 2) & 3);                               \
    }                                                                         \
    SBAR();                                                                   \
    BAR();                                                                    \
    LKW0(); SBAR();                                                           \
    MM16(0, a0, bb);                                                          \
    BAR();                                                                    \
    /* phase 2 */                                                             \
    RD_A4(a1, 4, BUFL);                                                       \
    if (DO_ST) {                                                              \
      STAGE_B32K((T) + 2, 0, ((BUFL) + 2) & 3);                               \
      STAGE_B32K((T) + 2, 1, ((BUFL) + 2) & 3);                               \
    }                                                                         \
    SBAR();                                                                   \
    BAR();                                                                    \
    LKW0(); SBAR();                                                           \
    MM16(4, a1, bb);                                                          \
    VMWSTMT;                                                                  \
    BAR();                                                                    \
  } while (0)

__global__ __launch_bounds__(512, 2) void gemm_256(
    const u16* __restrict__ xb, const u16* __restrict__ wt,
    const float* __restrict__ bias, float* __restrict__ out) {
  __shared__ __align__(16) u16 As[4 * 8192];   // ring-4 x (2 halves x 4096)
  __shared__ __align__(16) u16 Bs[4 * 8192];

  const int tid  = threadIdx.x;
  const int lane = tid & 63;
  const int wave = tid >> 6;
  const int wm   = wave >> 2;        // 0..1  (M)
  const int wn   = wave & 3;         // 0..3  (N)
  const int lrow = lane & 15;
  const int lk   = lane >> 4;        // k-granule 0..3

  // XCD-aware bijective block swizzle (valid when nwg % 8 == 0)
  const int nwg = gridDim.x * gridDim.y;
  int wg = blockIdx.y * gridDim.x + blockIdx.x;
  if ((nwg & 7) == 0) wg = (wg & 7) * (nwg >> 3) + (wg >> 3);
  const int bx = wg % gridDim.x;
  const int by = wg / gridDim.x;
  const int n0 = bx * 256;
  const int m0 = by * 256;

  const u16* at0 = xb + (size_t)(2 * by) * KT32N * 4096;
  const u16* bt0 = wt + (size_t)(2 * bx) * KT32N * 4096;

  // frag addresses: row r in half -> elem r*32 + slot*8, slot = lk^((r>>1)&3)
  const int aoff = wm * 4096 + lrow * 32;
  const int boff = (wn >> 1) * 4096 + ((wn & 1) * 64 + lrow) * 32;
  const int kq   = (lk ^ ((lrow >> 1) & 3)) * 8;

  bfv8 a0[4], a1[4], bb[4];
  f32x4 acc[8][4];
#pragma unroll
  for (int i = 0; i < 8; ++i)
#pragma unroll
    for (int j = 0; j < 4; ++j) acc[i][j] = f32x4{0.f, 0.f, 0.f, 0.f};

  // prologue: stage tiles 0,1 (8 loads in issue order A0,B0,A1,B1).
  // VMW(4) completes tile 0's 4 loads, leaves tile 1's 4 in flight —
  // the steady invariant (at tile-T end: T+1 resident, T+2 in flight).
  STAGE_A32K(0, 0, 0); STAGE_A32K(0, 1, 0);
  STAGE_B32K(0, 0, 0); STAGE_B32K(0, 1, 0);
  STAGE_A32K(1, 0, 1); STAGE_A32K(1, 1, 1);
  STAGE_B32K(1, 0, 1); STAGE_B32K(1, 1, 1);
  VMW(4); BAR();

#pragma unroll 1
  for (int t = 0; t < 124; t += 4) {   // tiles 0..123, stages 2..125
    KTILE32(t + 0, 0, 1, VMW(4));
    KTILE32(t + 1, 1, 1, VMW(4));
    KTILE32(t + 2, 2, 1, VMW(4));
    KTILE32(t + 3, 3, 1, VMW(4));
  }
  // tail: 124 stages 126; 125 stages 127; 126 drains; 127 pure compute
  KTILE32(124, 0, 1, VMW(4));
  KTILE32(125, 1, 1, VMW(4));
  KTILE32(126, 2, 0, VMW(0));
  KTILE32(127, 3, 0, (void)0);

  // epilogue: ref rounding f16(f16(acc) + bias); store f32.
  // C/D layout (m89): col = lane&15, row = (lane>>4)*4 + reg
#pragma unroll
  for (int j = 0; j < 4; ++j) {
    const int n = n0 + wn * 64 + j * 16 + lrow;
    const float bvf = bias[n];
#pragma unroll
    for (int i = 0; i < 8; ++i) {
      const int mrow = m0 + wm * 128 + i * 16 + lk * 4;
#pragma unroll
      for (int r = 0; r < 4; ++r) {
        out[(size_t)(mrow + r) * N_DIM + n] = f16r(f16r(acc[i][j][r]) + bvf);
      }
    }
  }
}

// ---------------------------------------------------------------------------
// Fused fallback (no workspace / odd M): R4 structure, register staging.
// ---------------------------------------------------------------------------
__global__ __launch_bounds__(256) void gemm_fused(
    const float* __restrict__ xf, const uint32_t* __restrict__ qw,
    const uint32_t* __restrict__ qzeros, const float* __restrict__ scales,
    const float* __restrict__ bias, float* __restrict__ out) {
  __shared__ __align__(16) u16 As[128 * LSTR];
  __shared__ __align__(16) u16 Bs[128 * LSTR];

  const int tid  = threadIdx.x;
  const int lane = tid & 63;
  const int wave = tid >> 6;
  const int n0 = blockIdx.x * 128;
  const int m0 = blockIdx.y * 128;
  const int m_off = (wave >> 1) * 64;
  const int n_off = (wave & 1) * 64;
  const int lrow  = lane & 15;
  const int lk    = lane >> 4;
  const int sm = tid >> 3;
  const int sc = tid & 7;

  f32x4 acc[4][4];
#pragma unroll
  for (int i = 0; i < 4; ++i)
#pragma unroll
    for (int j = 0; j < 4; ++j) acc[i][j] = f32x4{0.f, 0.f, 0.f, 0.f};

  const int ncol = n0 + (tid & 127);
  float s_cur = 0.f, nzs_cur = 0.f;

  for (int kt = 0; kt < K_DIM / 64; ++kt) {
    const int k0 = kt * 64;
    u16x8 av[4];
#pragma unroll
    for (int i = 0; i < 4; ++i) {
      const int m = i * 32 + sm;
      const float* sp = xf + (size_t)(m0 + m) * K_DIM + (k0 + sc * 8);
      const f32x4 p = *(const f32x4*)sp;
      const f32x4 q4 = *(const f32x4*)(sp + 4);
#pragma unroll
      for (int t = 0; t < 4; ++t) { av[i][t] = f2bf(p[t]); av[i][t+4] = f2bf(q4[t]); }
    }
    u16x8 bv[4];
    if ((k0 & (GS - 1)) == 0) {
      const int g = k0 >> 7;
      const uint32_t zq = qzeros[(size_t)g * (N_DIM / 8) + (ncol >> 3)];
      const int z = (int)((zq >> ((ncol & 7) * 4)) & 15u);
      s_cur = scales[(size_t)g * N_DIM + ncol];
      nzs_cur = -s_cur * (float)z;
    }
#pragma unroll
    for (int i = 0; i < 4; ++i) {
      const int k8l = (tid >> 7) + i * 2;
      const uint32_t q = qw[(size_t)(k0 / 8 + k8l) * N_DIM + ncol];
#pragma unroll
      for (int t = 0; t < 8; ++t) {
        const int qv = (int)((q >> (t * 4)) & 15u);
        bv[i][t] = f2bf(fmaf((float)qv, s_cur, nzs_cur));
      }
    }
#pragma unroll
    for (int i = 0; i < 4; ++i)
      *(u16x8*)&As[(i * 32 + sm) * LSTR + sc * 8] = av[i];
    {
      const int nl = tid & 127;
#pragma unroll
      for (int i = 0; i < 4; ++i) {
        const int k8l = (tid >> 7) + i * 2;
        *(u16x8*)&Bs[nl * LSTR + k8l * 8] = bv[i];
      }
    }
    __syncthreads();
#pragma unroll
    for (int ks = 0; ks < 2; ++ks) {
      const int c = (ks * 4 + lk) * 8;
      bfv8 a[4], b[4];
#pragma unroll
      for (int i = 0; i < 4; ++i)
        a[i] = __builtin_bit_cast(bfv8,
                 *(const u16x8*)&As[(m_off + i * 16 + lrow) * LSTR + c]);
#pragma unroll
      for (int j = 0; j < 4; ++j)
        b[j] = __builtin_bit_cast(bfv8,
                 *(const u16x8*)&Bs[(n_off + j * 16 + lrow) * LSTR + c]);
#pragma unroll
      for (int i = 0; i < 4; ++i)
#pragma unroll
        for (int j = 0; j < 4; ++j)
          acc[i][j] = __builtin_amdgcn_mfma_f32_16x16x32_bf16(a[i], b[j],
                                                              acc[i][j], 0, 0, 0);
    }
    __syncthreads();
  }
#pragma unroll
  for (int j = 0; j < 4; ++j) {
    const int n = n0 + n_off + j * 16 + lrow;
    const float bvf = bias[n];
#pragma unroll
    for (int i = 0; i < 4; ++i) {
      const int mrow = m0 + m_off + i * 16 + lk * 4;
#pragma unroll
      for (int r = 0; r < 4; ++r)
        out[(size_t)(mrow + r) * N_DIM + n] = f16r(f16r(acc[i][j][r]) + bvf);
    }
  }
}

extern "C" void kernel_launch(void* const* d_in, const int* in_sizes, int n_in,
                              void* d_out, int out_size, void* d_ws, size_t ws_size,
                              hipStream_t stream) {
  // Identify inputs by element count (all five distinct).
  const float* x = nullptr;      const uint32_t* qweight = nullptr;
  const uint32_t* qzeros = nullptr;
  const float* scales = nullptr; const float* bias = nullptr;
  int M = 4096;
  for (int i = 0; i < n_in; ++i) {
    const long long s = in_sizes[i];
    if      (s == (long long)(K_DIM / 8) * N_DIM) qweight = (const uint32_t*)d_in[i];
    else if (s == (long long)(K_DIM / GS) * (N_DIM / 8)) qzeros = (const uint32_t*)d_in[i];
    else if (s == (long long)(K_DIM / GS) * N_DIM) scales = (const float*)d_in[i];
    else if (s == (long long)N_DIM) bias = (const float*)d_in[i];
    else { x = (const float*)d_in[i]; M = (int)(s / K_DIM); }
  }
  float* out = (float*)d_out;

  const size_t xb_bytes = (size_t)M * K_DIM * sizeof(u16);      // 33.5 MB
  const size_t wt_bytes = (size_t)N_DIM * K_DIM * sizeof(u16);  // 90.2 MB

  if (ws_size >= xb_bytes + wt_bytes && (M % 256) == 0) {
    u16* xbp = (u16*)d_ws;
    u16* wtp = (u16*)((char*)d_ws + xb_bytes);
    convert_x32<<<dim3(KT32N, M / 128), 256, 0, stream>>>(x, xbp);
    dequant32<<<dim3(KT32N, N_DIM / 128), 256, 0, stream>>>(
        qweight, qzeros, scales, wtp);
    gemm_256<<<dim3(N_DIM / 256, M / 256), 512, 0, stream>>>(
        xbp, wtp, bias, out);
  } else {
    gemm_fused<<<dim3(N_DIM / 128, (M + 127) / 128), 256, 0, stream>>>(
        x, qweight, qzeros, scales, bias, out);
  }
}